// Round 2
// baseline (486.808 us; speedup 1.0000x reference)
//
#include <hip/hip_runtime.h>
#include <math.h>

#define EMB_D 64

// ---------------------------------------------------------------------------
// Kernel A1: coalesced f32 -> f64 codebook conversion (w64 in d_ws).
// ---------------------------------------------------------------------------
__global__ __launch_bounds__(256)
void vq_w64_kernel(const float* __restrict__ w, double* __restrict__ w64, int n) {
    int i = blockIdx.x * 256 + threadIdx.x;
    if (i < n) w64[i] = (double)w[i];
}

// ---------------------------------------------------------------------------
// Kernel A2: wsq[k] = numpy-emulated fp32 sum(w_k^2).
// numpy pairwise_sum for n=64 (<=128): 8 accumulators r[j] = sum_t a[j+8t]
// (sequential adds in t), then ((r0+r1)+(r2+r3)) + ((r4+r5)+(r6+r7)).
// __f*_rn intrinsics block ffp-contract fusion.
// ---------------------------------------------------------------------------
__global__ __launch_bounds__(256)
void vq_wsq_kernel(const float* __restrict__ w, float* __restrict__ wsq, int K) {
    int k = blockIdx.x * 256 + threadIdx.x;
    if (k >= K) return;
    const float* wr = w + (size_t)k * EMB_D;
    float r[8];
#pragma unroll
    for (int j = 0; j < 8; ++j) r[j] = __fmul_rn(wr[j], wr[j]);
#pragma unroll
    for (int t = 1; t < 8; ++t) {
#pragma unroll
        for (int j = 0; j < 8; ++j) {
            float sq = __fmul_rn(wr[t * 8 + j], wr[t * 8 + j]);
            r[j] = __fadd_rn(r[j], sq);
        }
    }
    float s01 = __fadd_rn(r[0], r[1]);
    float s23 = __fadd_rn(r[2], r[3]);
    float s45 = __fadd_rn(r[4], r[5]);
    float s67 = __fadd_rn(r[6], r[7]);
    float a   = __fadd_rn(s01, s23);
    float b   = __fadd_rn(s45, s67);
    wsq[k] = __fadd_rn(a, b);
}

// ---------------------------------------------------------------------------
// Kernel B: main. lane = row (64 rows/block), wave = contiguous ascending
// K-chunk of 256. Dot products in f64 (emulates a correctly-rounded fp32
// matmul after the cast); downstream rounding replicates numpy:
//   score = fl32( fl32(x_sq - fl32(2*M)) + w_sq )
// Argmin strict-< ascending k == np.argmin first-min tie-break.
// ---------------------------------------------------------------------------
__global__ __launch_bounds__(256, 2)
void vq_main_kernel(const float* __restrict__ x, const float* __restrict__ w,
                    const double* __restrict__ w64, const float* __restrict__ wsq,
                    float* __restrict__ out, float* __restrict__ blockloss,
                    int K, int N) {
    const int tid  = threadIdx.x;
    const int lane = tid & 63;
    const int wave = tid >> 6;
    const int row  = blockIdx.x * 64 + lane;

    // --- load x row (coalesced float4), scatter to scalars ---
    const float4* xrow4 = (const float4*)(x + (size_t)row * EMB_D);
    float xr[EMB_D];
#pragma unroll
    for (int i = 0; i < EMB_D / 4; ++i) {
        float4 v = xrow4[i];
        xr[4 * i + 0] = v.x; xr[4 * i + 1] = v.y;
        xr[4 * i + 2] = v.z; xr[4 * i + 3] = v.w;
    }

    // --- x_sq: numpy-emulated fp32 pairwise sum of squares ---
    float r[8];
#pragma unroll
    for (int j = 0; j < 8; ++j) r[j] = __fmul_rn(xr[j], xr[j]);
#pragma unroll
    for (int t = 1; t < 8; ++t) {
#pragma unroll
        for (int j = 0; j < 8; ++j) {
            float sq = __fmul_rn(xr[t * 8 + j], xr[t * 8 + j]);
            r[j] = __fadd_rn(r[j], sq);
        }
    }
    float s01 = __fadd_rn(r[0], r[1]);
    float s23 = __fadd_rn(r[2], r[3]);
    float s45 = __fadd_rn(r[4], r[5]);
    float s67 = __fadd_rn(r[6], r[7]);
    const float xsq = __fadd_rn(__fadd_rn(s01, s23), __fadd_rn(s45, s67));

    // --- x row to f64 registers ---
    double x64v[EMB_D];
#pragma unroll
    for (int i = 0; i < EMB_D; ++i) x64v[i] = (double)xr[i];

    const int kchunk = K >> 2;  // 4 waves split K in ascending chunks
    const int kbase  = __builtin_amdgcn_readfirstlane(wave * kchunk);

    float best = INFINITY;
    int   bidx = 0;
    for (int j = 0; j < kchunk; ++j) {
        const int k = kbase + j;                       // wave-uniform
        const double* wr = w64 + (size_t)k * EMB_D;    // uniform -> s_load
        double a0 = 0.0, a1 = 0.0, a2 = 0.0, a3 = 0.0;
#pragma unroll
        for (int i = 0; i < EMB_D; i += 4) {
            a0 = fma(x64v[i + 0], wr[i + 0], a0);
            a1 = fma(x64v[i + 1], wr[i + 1], a1);
            a2 = fma(x64v[i + 2], wr[i + 2], a2);
            a3 = fma(x64v[i + 3], wr[i + 3], a3);
        }
        const float mf = (float)((a0 + a1) + (a2 + a3));
        // numpy: (x_sq - 2.0*M) + w_sq, each op rounded in fp32
        const float t1 = __fmul_rn(2.0f, mf);
        const float t2 = __fsub_rn(xsq, t1);
        const float sc = __fadd_rn(t2, wsq[k]);
        if (sc < best) { best = sc; bidx = k; }        // first-min wins ties
    }

    // --- cross-wave argmin combine (waves are ascending k-chunks) ---
    __shared__ float lbest[4][64];
    __shared__ int   lidx[4][64];
    __shared__ int   fidx[64];
    lbest[wave][lane] = best;
    lidx[wave][lane]  = bidx;
    __syncthreads();
    if (wave == 0) {
        float b  = lbest[0][lane];
        int   bi = lidx[0][lane];
#pragma unroll
        for (int c = 1; c < 4; ++c) {
            float v = lbest[c][lane];
            if (v < b) { b = v; bi = lidx[c][lane]; }
        }
        fidx[lane] = bi;
        out[(size_t)N * EMB_D + row] = (float)bi;      // indices as f32
    }
    __syncthreads();

    // --- coalesced quantized write + loss partial ---
    float lpart = 0.f;
#pragma unroll
    for (int rep = 0; rep < 4; ++rep) {
        int f4   = rep * 256 + tid;   // 0..1023 float4s in this block
        int rr   = f4 >> 4;           // row within block
        int c    = f4 & 15;           // float4 within row
        int k    = fidx[rr];
        int grow = blockIdx.x * 64 + rr;
        float4 wv = ((const float4*)(w + (size_t)k * EMB_D))[c];
        float4 xq = ((const float4*)(x + (size_t)grow * EMB_D))[c];
        ((float4*)out)[(size_t)grow * (EMB_D / 4) + c] = wv;
        float dx = wv.x - xq.x, dy = wv.y - xq.y;
        float dz = wv.z - xq.z, dw = wv.w - xq.w;
        lpart += dx * dx + dy * dy + dz * dz + dw * dw;
    }
#pragma unroll
    for (int off = 32; off > 0; off >>= 1) lpart += __shfl_down(lpart, off);
    __shared__ float lred[4];
    if (lane == 0) lred[wave] = lpart;
    __syncthreads();
    if (tid == 0)
        blockloss[blockIdx.x] = (lred[0] + lred[1]) + (lred[2] + lred[3]);
}

// ---------------------------------------------------------------------------
// Kernel C: loss = 1.25 * mean((q - x)^2)
// ---------------------------------------------------------------------------
__global__ __launch_bounds__(256)
void vq_loss_kernel(const float* __restrict__ part, int nb,
                    float* __restrict__ out_loss, float scale) {
    float s = 0.f;
    for (int i = threadIdx.x; i < nb; i += 256) s += part[i];
#pragma unroll
    for (int off = 32; off > 0; off >>= 1) s += __shfl_down(s, off);
    __shared__ float red[4];
    int lane = threadIdx.x & 63, wave = threadIdx.x >> 6;
    if (lane == 0) red[wave] = s;
    __syncthreads();
    if (threadIdx.x == 0)
        out_loss[0] = ((red[0] + red[1]) + (red[2] + red[3])) * scale;
}

extern "C" void kernel_launch(void* const* d_in, const int* in_sizes, int n_in,
                              void* d_out, int out_size, void* d_ws, size_t ws_size,
                              hipStream_t stream) {
    const float* x = (const float*)d_in[0];
    const float* w = (const float*)d_in[1];
    float* out = (float*)d_out;
    const int xsz = in_sizes[0];   // N * D = 4194304
    const int wsz = in_sizes[1];   // K * D = 65536
    const int N   = xsz / EMB_D;   // 65536 rows
    const int K   = wsz / EMB_D;   // 1024 codewords
    const int NB  = N / 64;        // 1024 blocks

    // workspace layout: [w64: wsz doubles][wsq: K floats][blockloss: NB floats]
    double* w64      = (double*)d_ws;
    float*  wsq      = (float*)((char*)d_ws + (size_t)wsz * sizeof(double));
    float*  blockloss = wsq + K;

    vq_w64_kernel<<<(wsz + 255) / 256, 256, 0, stream>>>(w, w64, wsz);
    vq_wsq_kernel<<<(K + 255) / 256, 256, 0, stream>>>(w, wsq, K);
    vq_main_kernel<<<NB, 256, 0, stream>>>(x, w, w64, wsq, out, blockloss, K, N);
    vq_loss_kernel<<<1, 256, 0, stream>>>(blockloss, NB,
                                          out + (size_t)N * EMB_D + N,
                                          1.25f / (float)xsz);
}

// Round 3
// 454.862 us; speedup vs baseline: 1.0702x; 1.0702x over previous
//
#include <hip/hip_runtime.h>
#include <math.h>

#define EMB_D 64
#define MARGIN 2.0e-5f

// ---------------------------------------------------------------------------
// Kernel 1: wsq[k] = numpy-emulated fp32 sum(w_k^2)  (+ zero the suspect ctr).
// numpy pairwise_sum n=64: 8 accumulators r[j]=sum_t a[j+8t], then
// ((r0+r1)+(r2+r3)) + ((r4+r5)+(r6+r7)).
// ---------------------------------------------------------------------------
__global__ __launch_bounds__(256)
void vq_wsq_kernel(const float* __restrict__ w, float* __restrict__ wsq,
                   int* __restrict__ scount, int K) {
    if (blockIdx.x == 0 && threadIdx.x == 0) scount[0] = 0;
    int k = blockIdx.x * 256 + threadIdx.x;
    if (k >= K) return;
    const float* wr = w + (size_t)k * EMB_D;
    float r[8];
#pragma unroll
    for (int j = 0; j < 8; ++j) r[j] = __fmul_rn(wr[j], wr[j]);
#pragma unroll
    for (int t = 1; t < 8; ++t)
#pragma unroll
        for (int j = 0; j < 8; ++j)
            r[j] = __fadd_rn(r[j], __fmul_rn(wr[t * 8 + j], wr[t * 8 + j]));
    float a = __fadd_rn(__fadd_rn(r[0], r[1]), __fadd_rn(r[2], r[3]));
    float b = __fadd_rn(__fadd_rn(r[4], r[5]), __fadd_rn(r[6], r[7]));
    wsq[k] = __fadd_rn(a, b);
}

// ---------------------------------------------------------------------------
// Kernel 2: fp32 SCREEN. lane=row, wave=ascending k-chunk. Tracks top-2
// (s1,k1,s2) of s = wsq[k] - 2*x.w (fp32, |err| <= ~2e-8). Rows with
// s2-s1 <= MARGIN can't be decided at fp32-reference rounding granularity
// (~7.7e-6 per score) -> appended to suspect list for exact rescore.
// ---------------------------------------------------------------------------
__global__ __launch_bounds__(256, 4)
void vq_screen_kernel(const float* __restrict__ x, const float* __restrict__ w,
                      const float* __restrict__ wsq, int* __restrict__ fidx,
                      int* __restrict__ slist, int* __restrict__ scount,
                      int K, int N) {
    const int tid  = threadIdx.x;
    const int lane = tid & 63;
    const int wave = tid >> 6;
    const int row  = blockIdx.x * 64 + lane;

    const float4* xrow4 = (const float4*)(x + (size_t)row * EMB_D);
    float xr[EMB_D];
#pragma unroll
    for (int i = 0; i < EMB_D / 4; ++i) {
        float4 v = xrow4[i];
        xr[4 * i + 0] = v.x; xr[4 * i + 1] = v.y;
        xr[4 * i + 2] = v.z; xr[4 * i + 3] = v.w;
    }

    const int kchunk = K >> 2;
    const int kbase  = __builtin_amdgcn_readfirstlane(wave * kchunk);

    float s1 = INFINITY, s2 = INFINITY;
    int   k1 = kbase;
    for (int j = 0; j < kchunk; ++j) {
        const int k = kbase + j;                    // wave-uniform -> s_load
        const float* wr = w + (size_t)k * EMB_D;
        float a0 = 0.f, a1 = 0.f, a2 = 0.f, a3 = 0.f;
#pragma unroll
        for (int i = 0; i < EMB_D; i += 4) {
            a0 = fmaf(xr[i + 0], wr[i + 0], a0);
            a1 = fmaf(xr[i + 1], wr[i + 1], a1);
            a2 = fmaf(xr[i + 2], wr[i + 2], a2);
            a3 = fmaf(xr[i + 3], wr[i + 3], a3);
        }
        const float dot = (a0 + a1) + (a2 + a3);
        const float s   = fmaf(-2.0f, dot, wsq[k]);
        if (s < s1)      { s2 = s1; s1 = s; k1 = k; }  // strict <: first-min
        else if (s < s2) { s2 = s; }
    }

    __shared__ float L1[4][64], L2[4][64];
    __shared__ int   LI[4][64];
    L1[wave][lane] = s1; L2[wave][lane] = s2; LI[wave][lane] = k1;
    __syncthreads();
    if (wave == 0) {
        float g1 = L1[0][lane], g2 = L2[0][lane];
        int   gk = LI[0][lane];
#pragma unroll
        for (int c = 1; c < 4; ++c) {
            float a = L1[c][lane], b = L2[c][lane];
            int   ak = LI[c][lane];
            if (a < g1) { g2 = fminf(g1, b); g1 = a; gk = ak; }
            else        { g2 = fminf(g2, a); }
        }
        fidx[row] = gk;
        if (g2 - g1 <= MARGIN) {          // includes exact ties (g2==g1)
            int p = atomicAdd(scount, 1);
            slist[p] = row;
        }
    }
}

// ---------------------------------------------------------------------------
// Kernel 3: exact RESCORE of suspect rows (round-2 proven logic: f64 dot ->
// f32 cast -> numpy rounding chain; strict-< ascending-k argmin).
// Grid-stride over tiles of 64 suspect rows.
// ---------------------------------------------------------------------------
__global__ __launch_bounds__(256, 2)
void vq_rescore_kernel(const float* __restrict__ x, const float* __restrict__ w,
                       const float* __restrict__ wsq, int* __restrict__ fidx,
                       const int* __restrict__ slist,
                       const int* __restrict__ scount, int K, int N) {
    const int tid  = threadIdx.x;
    const int lane = tid & 63;
    const int wave = tid >> 6;
    const int cnt  = scount[0];

    __shared__ float lbest[4][64];
    __shared__ int   lidx[4][64];

    for (int tile = blockIdx.x; tile * 64 < cnt; tile += gridDim.x) {
        const int  li    = tile * 64 + lane;
        const bool valid = li < cnt;
        const int  row   = valid ? slist[li] : 0;

        const float4* xrow4 = (const float4*)(x + (size_t)row * EMB_D);
        float xr[EMB_D];
#pragma unroll
        for (int i = 0; i < EMB_D / 4; ++i) {
            float4 v = xrow4[i];
            xr[4 * i + 0] = v.x; xr[4 * i + 1] = v.y;
            xr[4 * i + 2] = v.z; xr[4 * i + 3] = v.w;
        }
        // numpy-emulated fp32 x_sq
        float r[8];
#pragma unroll
        for (int j = 0; j < 8; ++j) r[j] = __fmul_rn(xr[j], xr[j]);
#pragma unroll
        for (int t = 1; t < 8; ++t)
#pragma unroll
            for (int j = 0; j < 8; ++j)
                r[j] = __fadd_rn(r[j], __fmul_rn(xr[t * 8 + j], xr[t * 8 + j]));
        const float xsq = __fadd_rn(
            __fadd_rn(__fadd_rn(r[0], r[1]), __fadd_rn(r[2], r[3])),
            __fadd_rn(__fadd_rn(r[4], r[5]), __fadd_rn(r[6], r[7])));

        double x64v[EMB_D];
#pragma unroll
        for (int i = 0; i < EMB_D; ++i) x64v[i] = (double)xr[i];

        const int kchunk = K >> 2;
        const int kbase  = __builtin_amdgcn_readfirstlane(wave * kchunk);
        float best = INFINITY;
        int   bidx = 0;
        for (int j = 0; j < kchunk; ++j) {
            const int k = kbase + j;
            const float* wr = w + (size_t)k * EMB_D;   // uniform -> s_load
            double a0 = 0.0, a1 = 0.0, a2 = 0.0, a3 = 0.0;
#pragma unroll
            for (int i = 0; i < EMB_D; i += 4) {
                a0 = fma(x64v[i + 0], (double)wr[i + 0], a0);
                a1 = fma(x64v[i + 1], (double)wr[i + 1], a1);
                a2 = fma(x64v[i + 2], (double)wr[i + 2], a2);
                a3 = fma(x64v[i + 3], (double)wr[i + 3], a3);
            }
            const float mf = (float)((a0 + a1) + (a2 + a3));
            const float t2 = __fsub_rn(xsq, __fmul_rn(2.0f, mf));
            const float sc = __fadd_rn(t2, wsq[k]);
            if (sc < best) { best = sc; bidx = k; }
        }

        lbest[wave][lane] = best;
        lidx[wave][lane]  = bidx;
        __syncthreads();
        if (wave == 0 && valid) {
            float b  = lbest[0][lane];
            int   bi = lidx[0][lane];
#pragma unroll
            for (int c = 1; c < 4; ++c) {
                float v = lbest[c][lane];
                if (v < b) { b = v; bi = lidx[c][lane]; }
            }
            fidx[row] = bi;
        }
        __syncthreads();   // protect LDS reuse next tile
    }
}

// ---------------------------------------------------------------------------
// Kernel 4: gather/write quantized + indices + per-block loss partials.
// ---------------------------------------------------------------------------
__global__ __launch_bounds__(256)
void vq_gather_kernel(const float* __restrict__ x, const float* __restrict__ w,
                      const int* __restrict__ fidx, float* __restrict__ out,
                      float* __restrict__ blockloss, int N) {
    const int tid  = threadIdx.x;
    const int lane = tid & 63;
    const int wave = tid >> 6;
    __shared__ int kf[64];
    if (tid < 64) {
        int row = blockIdx.x * 64 + tid;
        int k = fidx[row];
        kf[tid] = k;
        out[(size_t)N * EMB_D + row] = (float)k;   // indices chunk as f32
    }
    __syncthreads();

    float lpart = 0.f;
#pragma unroll
    for (int rep = 0; rep < 4; ++rep) {
        int f4   = rep * 256 + tid;
        int rr   = f4 >> 4;
        int c    = f4 & 15;
        int k    = kf[rr];
        int grow = blockIdx.x * 64 + rr;
        float4 wv = ((const float4*)(w + (size_t)k * EMB_D))[c];
        float4 xq = ((const float4*)(x + (size_t)grow * EMB_D))[c];
        ((float4*)out)[(size_t)grow * (EMB_D / 4) + c] = wv;
        float dx = wv.x - xq.x, dy = wv.y - xq.y;
        float dz = wv.z - xq.z, dw = wv.w - xq.w;
        lpart += dx * dx + dy * dy + dz * dz + dw * dw;
    }
#pragma unroll
    for (int off = 32; off > 0; off >>= 1) lpart += __shfl_down(lpart, off);
    __shared__ float lred[4];
    if (lane == 0) lred[wave] = lpart;
    __syncthreads();
    if (tid == 0)
        blockloss[blockIdx.x] = (lred[0] + lred[1]) + (lred[2] + lred[3]);
}

// ---------------------------------------------------------------------------
// Kernel 5: loss = 1.25 * mean((q - x)^2)
// ---------------------------------------------------------------------------
__global__ __launch_bounds__(256)
void vq_loss_kernel(const float* __restrict__ part, int nb,
                    float* __restrict__ out_loss, float scale) {
    float s = 0.f;
    for (int i = threadIdx.x; i < nb; i += 256) s += part[i];
#pragma unroll
    for (int off = 32; off > 0; off >>= 1) s += __shfl_down(s, off);
    __shared__ float red[4];
    int lane = threadIdx.x & 63, wave = threadIdx.x >> 6;
    if (lane == 0) red[wave] = s;
    __syncthreads();
    if (threadIdx.x == 0)
        out_loss[0] = ((red[0] + red[1]) + (red[2] + red[3])) * scale;
}

extern "C" void kernel_launch(void* const* d_in, const int* in_sizes, int n_in,
                              void* d_out, int out_size, void* d_ws, size_t ws_size,
                              hipStream_t stream) {
    const float* x = (const float*)d_in[0];
    const float* w = (const float*)d_in[1];
    float* out = (float*)d_out;
    const int xsz = in_sizes[0];   // N * D
    const int wsz = in_sizes[1];   // K * D
    const int N   = xsz / EMB_D;   // 65536
    const int K   = wsz / EMB_D;   // 1024
    const int NB  = N / 64;        // 1024

    // ws layout: [scount:1 int (+pad 64)][slist:N int][fidx:N int][wsq:K f][blockloss:NB f]
    int*   scount    = (int*)d_ws;
    int*   slist     = scount + 64;
    int*   fidx      = slist + N;
    float* wsq       = (float*)(fidx + N);
    float* blockloss = wsq + K;

    vq_wsq_kernel<<<(K + 255) / 256, 256, 0, stream>>>(w, wsq, scount, K);
    vq_screen_kernel<<<NB, 256, 0, stream>>>(x, w, wsq, fidx, slist, scount, K, N);
    vq_rescore_kernel<<<256, 256, 0, stream>>>(x, w, wsq, fidx, slist, scount, K, N);
    vq_gather_kernel<<<NB, 256, 0, stream>>>(x, w, fidx, out, blockloss, N);
    vq_loss_kernel<<<1, 256, 0, stream>>>(blockloss, NB,
                                          out + (size_t)N * EMB_D + N,
                                          1.25f / (float)xsz);
}